// Round 13
// baseline (206.066 us; speedup 1.0000x reference)
//
#include <hip/hip_runtime.h>
#include <cfloat>
#include <climits>

#define B_DIM 16
#define C_DIM 64
#define N_DIM 2048
#define O_DIM 64
#define K_NN  3

typedef __attribute__((ext_vector_type(8))) short bf16x8;
typedef __attribute__((ext_vector_type(4))) float floatx4;

__device__ __forceinline__ unsigned short f32_to_bf16_rne(float f) {
  unsigned int u = __float_as_uint(f);
  return (unsigned short)((u + 0x7fffu + ((u >> 16) & 1u)) >> 16);
}
__device__ __forceinline__ float bf16_to_f32(unsigned short h) {
  return __uint_as_float(((unsigned int)h) << 16);
}

// med3 on u32 (compiler pattern-matches to v_med3_u32)
__device__ __forceinline__ unsigned med3u(unsigned a, unsigned b, unsigned c) {
  unsigned mn = min(a, b), mx = max(a, b);
  return max(mn, min(mx, c));
}

// paired (packed-key, j) branchless top-4 insert — merge phase only
__device__ __forceinline__ void ins4p(unsigned u, int jv, unsigned* k, int* j) {
  bool c3 = u < k[3], c2 = u < k[2], c1 = u < k[1], c0 = u < k[0];
  k[3] = c2 ? k[2] : (c3 ? u  : k[3]);
  j[3] = c2 ? j[2] : (c3 ? jv : j[3]);
  k[2] = c1 ? k[1] : (c2 ? u  : k[2]);
  j[2] = c1 ? j[1] : (c2 ? jv : j[2]);
  k[1] = c0 ? k[0] : (c1 ? u  : k[1]);
  j[1] = c0 ? j[0] : (c1 ? jv : j[1]);
  k[0] = c0 ? u  : k[0];
  j[0] = c0 ? jv : j[0];
}

// ---- kernel 1: x -> xT fp32 [B][N][C], bf16 hi/lo split (chunk-swizzled:
// 16B chunk q of row n stored at q^(n&7)), fp64 norms nd, fp32 norms+512.
// Blocks >= 512 do the W transpose. ----
__global__ __launch_bounds__(256) void prep_kernel(
    const float* __restrict__ x, float* __restrict__ xT,
    unsigned short* __restrict__ xTh, unsigned short* __restrict__ xTl,
    double* __restrict__ nd, float* __restrict__ nf,
    const float* __restrict__ W, float* __restrict__ Wt) {
  int bid = blockIdx.x;
  int t = threadIdx.x;
  if (bid >= 512) {                  // W transpose: 48 blocks
    int t2 = (bid - 512) * 256 + t;  // 12288 = O * C * K
    int o  = t2 / (C_DIM * K_NN);
    int ck = t2 - o * (C_DIM * K_NN);
    Wt[ck * O_DIM + o] = W[t2];
    return;
  }
  __shared__ __align__(16) float xs[C_DIM][68];
  int b  = bid >> 5;
  int n0 = (bid & 31) * 64;
  const float* xb = x + (size_t)b * C_DIM * N_DIM;
  #pragma unroll
  for (int r = 0; r < 4; ++r) {
    int idx = r * 256 + t;           // 1024 float4 tasks
    int c = idx >> 4;
    int qq = idx & 15;
    *(float4*)&xs[c][qq * 4] = *(const float4*)(xb + (size_t)c * N_DIM + n0 + qq * 4);
  }
  __syncthreads();
  int n = t >> 2, cg = t & 3;        // 64 n x 4 c-groups of 16
  float v[16];
  #pragma unroll
  for (int cc = 0; cc < 16; ++cc) v[cc] = xs[cg * 16 + cc][n];
  double ps = 0.0;
  #pragma unroll
  for (int cc = 0; cc < 16; ++cc) ps = fma((double)v[cc], (double)v[cc], ps);
  ps += __shfl_xor(ps, 1, 64);
  ps += __shfl_xor(ps, 2, 64);       // lanes t^1,t^2 share n
  size_t row = (size_t)b * N_DIM + n0 + n;
  #pragma unroll
  for (int qq = 0; qq < 4; ++qq) {
    float4 wv; wv.x = v[qq*4]; wv.y = v[qq*4+1]; wv.z = v[qq*4+2]; wv.w = v[qq*4+3];
    *(float4*)&xT[row * C_DIM + cg * 16 + qq * 4] = wv;
  }
  unsigned short hh[16], ll[16];
  #pragma unroll
  for (int cc = 0; cc < 16; ++cc) {
    hh[cc] = f32_to_bf16_rne(v[cc]);
    ll[cc] = f32_to_bf16_rne(v[cc] - bf16_to_f32(hh[cc]));
  }
  #pragma unroll
  for (int e = 0; e < 2; ++e) {
    int phys = (2 * cg + e) ^ (n & 7);
    unsigned int hp[4], lp[4];
    #pragma unroll
    for (int xk = 0; xk < 4; ++xk) {
      hp[xk] = (unsigned)hh[e*8 + 2*xk] | ((unsigned)hh[e*8 + 2*xk + 1] << 16);
      lp[xk] = (unsigned)ll[e*8 + 2*xk] | ((unsigned)ll[e*8 + 2*xk + 1] << 16);
    }
    ((uint4*)xTh)[row * 8 + phys] = *(uint4*)hp;
    ((uint4*)xTl)[row * 8 + phys] = *(uint4*)lp;
  }
  if (cg == 0) {
    nd[row] = ps;
    nf[row] = (float)ps + 512.0f;    // pre-biased: key' = fma(-2,acc,nf) > 0
  }
}

// ---- kernel 2: split-bf16 MFMA distance sweep, packed-u32 top-4,
// register-prefetch pipelined staging ----
// grid = B*32*4 = 2048 blocks (64-row itile x j-quarter), 256 thr.
// A = J-tile (LDS 32KB), B = I-frags (regs). Per js-step: barrier ->
// LDS store (from prefetch regs) -> barrier -> ISSUE next tile's global
// loads -> MFMA+epilogue. The compiler's vmcnt(0) drain before the next
// top-barrier lands after the compute section, hiding the L2 latency
// that made r12 50% stall (VALUBusy 33 + MfmaUtil 18).
__global__ __launch_bounds__(256, 4) void topk_kernel(
    const unsigned short* __restrict__ xTh, const unsigned short* __restrict__ xTl,
    const float* __restrict__ nf, unsigned short* __restrict__ cand) {
  __shared__ __align__(16) unsigned short Jh[128 * 64];  // 16 KB
  __shared__ __align__(16) unsigned short Jl[128 * 64];  // 16 KB
  int bid   = blockIdx.x;
  int q     = bid & 3;               // j-quarter
  int itile = (bid >> 2) & 31;       // 32 i-tiles of 64 rows
  int b     = bid >> 7;
  int i0    = itile * 64;
  int jq0   = q * 512;
  int t = threadIdx.x;
  int w = t >> 6, lane = t & 63, quad = lane >> 4, col = lane & 15;
  int csw = col & 7;
  const unsigned short* xh = xTh + (size_t)b * N_DIM * 64;
  const unsigned short* xl = xTl + (size_t)b * N_DIM * 64;
  const float* nfb = nf + b * N_DIM;

  // I-frags (B operand) once from global. row&7 == col&7 == csw.
  bf16x8 ih[2], il[2];
  #pragma unroll
  for (int ks = 0; ks < 2; ++ks) {
    size_t row = i0 + w * 16 + col;
    int phys = (ks * 4 + quad) ^ csw;
    ih[ks] = *(const bf16x8*)(xh + row * 64 + phys * 8);
    il[ks] = *(const bf16x8*)(xl + row * 64 + phys * 8);
  }

  unsigned ck[4];
  ck[0] = ck[1] = ck[2] = ck[3] = 0xFFFFFFFFu;

  int a0 = col * 64 + ((quad ^ csw) * 8);        // ks=0 frag offset (shorts)
  int a1 = col * 64 + (((4 + quad) ^ csw) * 8);  // ks=1

  // staging pointers (verbatim 16B copies, layout already split+swizzled)
  const unsigned short* sbh = xh + (size_t)(jq0 + w * 32) * 64 + lane * 8;
  const unsigned short* sbl = xl + (size_t)(jq0 + w * 32) * 64 + lane * 8;
  unsigned short* dsh = &Jh[w * 32 * 64] + lane * 8;
  unsigned short* dsl = &Jl[w * 32 * 64] + lane * 8;

  // prefetch tile js=0
  uint4 ph[4], pl[4];
  #pragma unroll
  for (int k2 = 0; k2 < 4; ++k2) {
    ph[k2] = *(const uint4*)(sbh + k2 * 512);
    pl[k2] = *(const uint4*)(sbl + k2 * 512);
  }

  #pragma unroll
  for (int js = 0; js < 4; ++js) {
    int j0 = jq0 + js * 128;
    __syncthreads();                 // prior frag reads done before overwrite
    #pragma unroll
    for (int k2 = 0; k2 < 4; ++k2) {
      *(uint4*)(dsh + k2 * 512) = ph[k2];
      *(uint4*)(dsl + k2 * 512) = pl[k2];
    }
    __syncthreads();

    // issue next tile's loads now; latency overlaps MFMA + epilogue
    if (js < 3) {
      #pragma unroll
      for (int k2 = 0; k2 < 4; ++k2) {
        ph[k2] = *(const uint4*)(sbh + (js + 1) * 8192 + k2 * 512);
        pl[k2] = *(const uint4*)(sbl + (js + 1) * 8192 + k2 * 512);
      }
    }

    floatx4 acc[8];
    #pragma unroll
    for (int jt = 0; jt < 8; ++jt) acc[jt] = (floatx4){0.f, 0.f, 0.f, 0.f};

    #pragma unroll
    for (int ks = 0; ks < 2; ++ks) {
      int ab = ks ? a1 : a0;
      #pragma unroll
      for (int jt = 0; jt < 8; ++jt) {
        bf16x8 jh = *(const bf16x8*)&Jh[jt * 1024 + ab];
        bf16x8 jl = *(const bf16x8*)&Jl[jt * 1024 + ab];
        acc[jt] = __builtin_amdgcn_mfma_f32_16x16x32_bf16(jl, ih[ks], acc[jt], 0, 0, 0);
        acc[jt] = __builtin_amdgcn_mfma_f32_16x16x32_bf16(jh, il[ks], acc[jt], 0, 0, 0);
        acc[jt] = __builtin_amdgcn_mfma_f32_16x16x32_bf16(jh, ih[ks], acc[jt], 0, 0, 0);
      }
    }

    // epilogue: key' = nf512[j] - 2*dot (> 0); pack (bits & ~127) |
    // (js<<5 | jt*4+r); sorted top-4 via min + 3 med3.
    unsigned locb = (unsigned)(js << 5);
    int jb = j0 + quad * 4;
    #pragma unroll
    for (int jt = 0; jt < 8; ++jt) {
      float4 nv = *(const float4*)(nfb + jb + jt * 16);
      float nfa[4] = {nv.x, nv.y, nv.z, nv.w};
      #pragma unroll
      for (int r = 0; r < 4; ++r) {
        float key = fmaf(-2.0f, acc[jt][r], nfa[r]);
        unsigned u = (__float_as_uint(key) & 0xFFFFFF80u) | locb |
                     (unsigned)(jt * 4 + r);
        unsigned m0 = min(ck[0], u);
        unsigned m1 = med3u(ck[0], u, ck[1]);
        unsigned m2 = med3u(ck[1], u, ck[2]);
        unsigned m3 = med3u(ck[2], u, ck[3]);
        ck[0] = m0; ck[1] = m1; ck[2] = m2; ck[3] = m3;
      }
    }
  }

  // decode stream-local ids -> global j (quad known only pre-merge)
  int cj[4];
  #pragma unroll
  for (int s = 0; s < 4; ++s) {
    unsigned loc = ck[s] & 127u;
    cj[s] = jq0 + (int)((loc >> 5) << 7) + (int)(((loc >> 2) & 7u) << 4) +
            (quad << 2) + (int)(loc & 3u);
  }
  // paired merge across the 4 quads holding the same col (= same i-row)
  #pragma unroll
  for (int m = 16; m < 64; m <<= 1) {
    unsigned tu[4]; int tj[4];
    #pragma unroll
    for (int s = 0; s < 4; ++s) {
      tu[s] = __shfl_xor(ck[s], m, 64);
      tj[s] = __shfl_xor(cj[s], m, 64);
    }
    #pragma unroll
    for (int s = 0; s < 4; ++s) ins4p(tu[s], tj[s], ck, cj);
  }
  if (quad == 0) {
    int row = b * N_DIM + i0 + w * 16 + col;
    unsigned short* cp = cand + row * 16 + q * 4;
    cp[0] = (unsigned short)cj[0];
    cp[1] = (unsigned short)cj[1];
    cp[2] = (unsigned short)cj[2];
    cp[3] = (unsigned short)cj[3];
  }
}

// ---- kernel 3: fused exact-fp64 refine + gather + conv ----
#define NT   64
#define NPAD 68
__global__ __launch_bounds__(256) void conv_kernel(
    const float* __restrict__ xT, const double* __restrict__ nd,
    const unsigned short* __restrict__ cand,
    const float* __restrict__ Wt, const float* __restrict__ bias,
    float* __restrict__ out) {
  __shared__ __align__(16) float nb[C_DIM * K_NN][NPAD];  // 52224 B
  __shared__ unsigned short tks[NT][4];
  int bid = blockIdx.x;
  int b  = bid >> 5;
  int n0 = (bid & 31) * NT;
  const float* xtb = xT + (size_t)b * N_DIM * C_DIM;
  int t = threadIdx.x;
  int w = t >> 6, lane = t & 63;
  int cid = lane >> 2, seg = lane & 3;

  // ---- refine phase: 16 rows per wave ----
  for (int it = 0; it < 16; ++it) {
    int nn = w * 16 + it;
    int row = b * N_DIM + n0 + nn;
    int j = cand[row * 16 + cid];
    const float* xn = xtb + ((size_t)(n0 + nn) * C_DIM) + seg * 16;
    const float* xj = xtb + ((size_t)j * C_DIM) + seg * 16;
    double pd = 0.0;
    #pragma unroll
    for (int qq = 0; qq < 4; ++qq) {
      float4 a  = *(const float4*)(xn + qq * 4);
      float4 bb = *(const float4*)(xj + qq * 4);
      pd = fma((double)a.x, (double)bb.x, pd);
      pd = fma((double)a.y, (double)bb.y, pd);
      pd = fma((double)a.z, (double)bb.z, pd);
      pd = fma((double)a.w, (double)bb.w, pd);
    }
    pd += __shfl_xor(pd, 1, 64);     // reduce over seg
    pd += __shfl_xor(pd, 2, 64);
    double key = fma(-2.0, pd, nd[b * N_DIM + j] + 512.0);  // > 0 always
    unsigned long long u =
        ((unsigned long long)__double_as_longlong(key) & ~2047ull) |
        (unsigned long long)(unsigned)j;
    unsigned long long v = u;
    #pragma unroll
    for (int p = 0; p < 3; ++p) {
      unsigned long long m = v;
      #pragma unroll
      for (int msk = 4; msk < 64; msk <<= 1) {
        unsigned long long o = __shfl_xor(m, msk, 64);
        m = (o < m) ? o : m;
      }
      if (lane == 0) tks[nn][p] = (unsigned short)(m & 2047ull);
      v = (v == m) ? ~0ull : v;      // mask winner (and all equal copies)
    }
  }
  __syncthreads();

  // ---- gather phase ----
  #pragma unroll
  for (int p = 0; p < 12; ++p) {
    int u = p * 256 + t;            // 3072 tasks: 192 rows x 16 segs
    int sg = u & 15;
    int r  = u >> 4;                // r = k*64 + n
    int k = r >> 6, n = r & 63;
    int j = tks[n][k];
    float4 v = *(const float4*)(xtb + (size_t)j * C_DIM + sg * 4);
    nb[(sg * 4 + 0) * 3 + k][n] = v.x;
    nb[(sg * 4 + 1) * 3 + k][n] = v.y;
    nb[(sg * 4 + 2) * 3 + k][n] = v.z;
    nb[(sg * 4 + 3) * 3 + k][n] = v.w;
  }
  __syncthreads();

  // ---- conv phase ----
  int ng = t & 15, og = t >> 4;
  float acc[4][4];
  #pragma unroll
  for (int oo = 0; oo < 4; ++oo) {
    float bv = bias[(og << 2) + oo];
    #pragma unroll
    for (int nn2 = 0; nn2 < 4; ++nn2) acc[oo][nn2] = bv;
  }
  const float* nbp = &nb[0][0] + (ng << 2);
  const float* wtp = Wt + (og << 2);
  #pragma unroll 4
  for (int ckk = 0; ckk < C_DIM * K_NN; ++ckk) {
    float4 nv = *(const float4*)(nbp + ckk * NPAD);
    float4 wv = *(const float4*)(wtp + ckk * O_DIM);
    float na[4] = {nv.x, nv.y, nv.z, nv.w};
    float wa[4] = {wv.x, wv.y, wv.z, wv.w};
    #pragma unroll
    for (int oo = 0; oo < 4; ++oo)
      #pragma unroll
      for (int nn2 = 0; nn2 < 4; ++nn2)
        acc[oo][nn2] = fmaf(wa[oo], na[nn2], acc[oo][nn2]);
  }
  #pragma unroll
  for (int oo = 0; oo < 4; ++oo) {
    int o = (og << 2) + oo;
    float4 v; v.x = acc[oo][0]; v.y = acc[oo][1]; v.z = acc[oo][2]; v.w = acc[oo][3];
    *(float4*)&out[(size_t)(b * O_DIM + o) * N_DIM + n0 + (ng << 2)] = v;
  }
}

extern "C" void kernel_launch(void* const* d_in, const int* in_sizes, int n_in,
                              void* d_out, int out_size, void* d_ws, size_t ws_size,
                              hipStream_t stream) {
  const float* x    = (const float*)d_in[0];   // [B][C][N]
  const float* W    = (const float*)d_in[1];   // [O][C][K]
  const float* bias = (const float*)d_in[2];   // [O]
  float* out = (float*)d_out;                  // [B][O][N]
  char* ws = (char*)d_ws;
  // ws layout (bytes):
  //   xT   fp32 [B][N][C]           @ 0         (8 MB)
  //   xTh  bf16 [B][N][C] swizzled  @ 8388608   (4 MB)
  //   xTl  bf16 [B][N][C] swizzled  @ 12582912  (4 MB)
  //   nd   fp64 [B*N]               @ 16777216  (256 KB)
  //   nf   fp32 [B*N] (norm+512)    @ 17039360  (128 KB)
  //   cand u16  [B*N][16]           @ 17170432  (1 MB)
  //   Wt   fp32 [C*K][O]            @ 18219008  (48 KB)
  float*          xT  = (float*)ws;
  unsigned short* xTh = (unsigned short*)(ws + 8388608);
  unsigned short* xTl = (unsigned short*)(ws + 12582912);
  double*         nd  = (double*)(ws + 16777216);
  float*          nfp = (float*)(ws + 17039360);
  unsigned short* cd  = (unsigned short*)(ws + 17170432);
  float*          Wt  = (float*)(ws + 18219008);

  prep_kernel<<<512 + 48, 256, 0, stream>>>(x, xT, xTh, xTl, nd, nfp, W, Wt);
  topk_kernel<<<B_DIM * 32 * 4, 256, 0, stream>>>(xTh, xTl, nfp, cd);
  conv_kernel<<<B_DIM * (N_DIM / NT), 256, 0, stream>>>(xT, nd, cd, Wt, bias, out);
}

// Round 14
// 154.810 us; speedup vs baseline: 1.3311x; 1.3311x over previous
//
#include <hip/hip_runtime.h>
#include <cfloat>
#include <climits>

#define B_DIM 16
#define C_DIM 64
#define N_DIM 2048
#define O_DIM 64
#define K_NN  3

typedef __attribute__((ext_vector_type(8))) short bf16x8;
typedef __attribute__((ext_vector_type(4))) float floatx4;

// async global->LDS DMA, 16B/lane: LDS dest = uniform base + lane*16
#define GLDS16(gsrc, ldst)                                        \
  __builtin_amdgcn_global_load_lds(                               \
      (const __attribute__((address_space(1))) void*)(gsrc),      \
      (__attribute__((address_space(3))) void*)(ldst), 16, 0, 0)

__device__ __forceinline__ unsigned short f32_to_bf16_rne(float f) {
  unsigned int u = __float_as_uint(f);
  return (unsigned short)((u + 0x7fffu + ((u >> 16) & 1u)) >> 16);
}
__device__ __forceinline__ float bf16_to_f32(unsigned short h) {
  return __uint_as_float(((unsigned int)h) << 16);
}

// med3 on u32 (compiler pattern-matches to v_med3_u32)
__device__ __forceinline__ unsigned med3u(unsigned a, unsigned b, unsigned c) {
  unsigned mn = min(a, b), mx = max(a, b);
  return max(mn, min(mx, c));
}

// paired (packed-key, j) branchless top-4 insert — merge phase only
__device__ __forceinline__ void ins4p(unsigned u, int jv, unsigned* k, int* j) {
  bool c3 = u < k[3], c2 = u < k[2], c1 = u < k[1], c0 = u < k[0];
  k[3] = c2 ? k[2] : (c3 ? u  : k[3]);
  j[3] = c2 ? j[2] : (c3 ? jv : j[3]);
  k[2] = c1 ? k[1] : (c2 ? u  : k[2]);
  j[2] = c1 ? j[1] : (c2 ? jv : j[2]);
  k[1] = c0 ? k[0] : (c1 ? u  : k[1]);
  j[1] = c0 ? j[0] : (c1 ? jv : j[1]);
  k[0] = c0 ? u  : k[0];
  j[0] = c0 ? jv : j[0];
}

// ---- kernel 1: x -> xT fp32 [B][N][C], bf16 hi/lo split (chunk-swizzled:
// 16B chunk q of row n stored at q^(n&7)), fp64 norms nd, fp32 norms+512.
// Blocks >= 512 do the W transpose. ----
__global__ __launch_bounds__(256) void prep_kernel(
    const float* __restrict__ x, float* __restrict__ xT,
    unsigned short* __restrict__ xTh, unsigned short* __restrict__ xTl,
    double* __restrict__ nd, float* __restrict__ nf,
    const float* __restrict__ W, float* __restrict__ Wt) {
  int bid = blockIdx.x;
  int t = threadIdx.x;
  if (bid >= 512) {                  // W transpose: 48 blocks
    int t2 = (bid - 512) * 256 + t;  // 12288 = O * C * K
    int o  = t2 / (C_DIM * K_NN);
    int ck = t2 - o * (C_DIM * K_NN);
    Wt[ck * O_DIM + o] = W[t2];
    return;
  }
  __shared__ __align__(16) float xs[C_DIM][68];
  int b  = bid >> 5;
  int n0 = (bid & 31) * 64;
  const float* xb = x + (size_t)b * C_DIM * N_DIM;
  #pragma unroll
  for (int r = 0; r < 4; ++r) {
    int idx = r * 256 + t;           // 1024 float4 tasks
    int c = idx >> 4;
    int qq = idx & 15;
    *(float4*)&xs[c][qq * 4] = *(const float4*)(xb + (size_t)c * N_DIM + n0 + qq * 4);
  }
  __syncthreads();
  int n = t >> 2, cg = t & 3;        // 64 n x 4 c-groups of 16
  float v[16];
  #pragma unroll
  for (int cc = 0; cc < 16; ++cc) v[cc] = xs[cg * 16 + cc][n];
  double ps = 0.0;
  #pragma unroll
  for (int cc = 0; cc < 16; ++cc) ps = fma((double)v[cc], (double)v[cc], ps);
  ps += __shfl_xor(ps, 1, 64);
  ps += __shfl_xor(ps, 2, 64);       // lanes t^1,t^2 share n
  size_t row = (size_t)b * N_DIM + n0 + n;
  #pragma unroll
  for (int qq = 0; qq < 4; ++qq) {
    float4 wv; wv.x = v[qq*4]; wv.y = v[qq*4+1]; wv.z = v[qq*4+2]; wv.w = v[qq*4+3];
    *(float4*)&xT[row * C_DIM + cg * 16 + qq * 4] = wv;
  }
  unsigned short hh[16], ll[16];
  #pragma unroll
  for (int cc = 0; cc < 16; ++cc) {
    hh[cc] = f32_to_bf16_rne(v[cc]);
    ll[cc] = f32_to_bf16_rne(v[cc] - bf16_to_f32(hh[cc]));
  }
  #pragma unroll
  for (int e = 0; e < 2; ++e) {
    int phys = (2 * cg + e) ^ (n & 7);
    unsigned int hp[4], lp[4];
    #pragma unroll
    for (int xk = 0; xk < 4; ++xk) {
      hp[xk] = (unsigned)hh[e*8 + 2*xk] | ((unsigned)hh[e*8 + 2*xk + 1] << 16);
      lp[xk] = (unsigned)ll[e*8 + 2*xk] | ((unsigned)ll[e*8 + 2*xk + 1] << 16);
    }
    ((uint4*)xTh)[row * 8 + phys] = *(uint4*)hp;
    ((uint4*)xTl)[row * 8 + phys] = *(uint4*)lp;
  }
  if (cg == 0) {
    nd[row] = ps;
    nf[row] = (float)ps + 512.0f;    // pre-biased: key' = fma(-2,acc,nf) > 0
  }
}

// ---- kernel 2: split-bf16 MFMA distance sweep, packed-u32 top-4,
// double-buffered global_load_lds staging ----
// grid = B*32*4 = 2048 blocks (64-row itile x j-quarter), 256 thr.
// LDS 2 x (Jh+Jl) = 64 KB exactly -> (256,2), 2 blocks/CU, VGPR cap 256
// (no spill possible — the r13 register-prefetch spill lesson).
// Per step: issue DMA for tile js+1 into buf^1, MFMA+epilogue on buf,
// ONE barrier (its vmcnt drain lands after ~900 cyc of compute, hiding
// the L2 latency that left r12 at 50% stall). Staging layout is already
// the DMA shape: uniform LDS base + lane*16B, swizzle pre-baked by prep.
__global__ __launch_bounds__(256, 2) void topk_kernel(
    const unsigned short* __restrict__ xTh, const unsigned short* __restrict__ xTl,
    const float* __restrict__ nf, unsigned short* __restrict__ cand) {
  __shared__ __align__(16) unsigned short Jh[2][128 * 64];  // 2 x 16 KB
  __shared__ __align__(16) unsigned short Jl[2][128 * 64];  // 2 x 16 KB
  int bid   = blockIdx.x;
  int q     = bid & 3;               // j-quarter
  int itile = (bid >> 2) & 31;       // 32 i-tiles of 64 rows
  int b     = bid >> 7;
  int i0    = itile * 64;
  int jq0   = q * 512;
  int t = threadIdx.x;
  int w = t >> 6, lane = t & 63, quad = lane >> 4, col = lane & 15;
  int csw = col & 7;
  const unsigned short* xh = xTh + (size_t)b * N_DIM * 64;
  const unsigned short* xl = xTl + (size_t)b * N_DIM * 64;
  const float* nfb = nf + b * N_DIM;

  // I-frags (B operand) once from global. row&7 == col&7 == csw.
  bf16x8 ih[2], il[2];
  #pragma unroll
  for (int ks = 0; ks < 2; ++ks) {
    size_t row = i0 + w * 16 + col;
    int phys = (ks * 4 + quad) ^ csw;
    ih[ks] = *(const bf16x8*)(xh + row * 64 + phys * 8);
    il[ks] = *(const bf16x8*)(xl + row * 64 + phys * 8);
  }

  unsigned ck[4];
  ck[0] = ck[1] = ck[2] = ck[3] = 0xFFFFFFFFu;

  int a0 = col * 64 + ((quad ^ csw) * 8);        // ks=0 frag offset (shorts)
  int a1 = col * 64 + (((4 + quad) ^ csw) * 8);  // ks=1

  // per-lane global source base (tile js, chunk k2: + js*8192 + k2*512)
  const unsigned short* sbh = xh + (size_t)(jq0 + w * 32) * 64 + lane * 8;
  const unsigned short* sbl = xl + (size_t)(jq0 + w * 32) * 64 + lane * 8;
  int ldsb = w * 32 * 64;            // wave-uniform LDS base (shorts)

  // prologue: DMA tile 0 into buf 0
  #pragma unroll
  for (int k2 = 0; k2 < 4; ++k2) {
    GLDS16(sbh + k2 * 512, &Jh[0][ldsb + k2 * 512]);
    GLDS16(sbl + k2 * 512, &Jl[0][ldsb + k2 * 512]);
  }
  __syncthreads();                   // drain: buf0 ready

  #pragma unroll
  for (int js = 0; js < 4; ++js) {
    int cur = js & 1, nxt = cur ^ 1;
    int j0 = jq0 + js * 128;

    // issue DMA for tile js+1; buf[nxt] was sealed by the last barrier
    if (js < 3) {
      #pragma unroll
      for (int k2 = 0; k2 < 4; ++k2) {
        GLDS16(sbh + (js + 1) * 8192 + k2 * 512, &Jh[nxt][ldsb + k2 * 512]);
        GLDS16(sbl + (js + 1) * 8192 + k2 * 512, &Jl[nxt][ldsb + k2 * 512]);
      }
    }

    floatx4 acc[8];
    #pragma unroll
    for (int jt = 0; jt < 8; ++jt) acc[jt] = (floatx4){0.f, 0.f, 0.f, 0.f};

    #pragma unroll
    for (int ks = 0; ks < 2; ++ks) {
      int ab = ks ? a1 : a0;
      #pragma unroll
      for (int jt = 0; jt < 8; ++jt) {
        bf16x8 jh = *(const bf16x8*)&Jh[cur][jt * 1024 + ab];
        bf16x8 jl = *(const bf16x8*)&Jl[cur][jt * 1024 + ab];
        acc[jt] = __builtin_amdgcn_mfma_f32_16x16x32_bf16(jl, ih[ks], acc[jt], 0, 0, 0);
        acc[jt] = __builtin_amdgcn_mfma_f32_16x16x32_bf16(jh, il[ks], acc[jt], 0, 0, 0);
        acc[jt] = __builtin_amdgcn_mfma_f32_16x16x32_bf16(jh, ih[ks], acc[jt], 0, 0, 0);
      }
    }

    // epilogue: key' = nf512[j] - 2*dot (> 0); pack (bits & ~127) |
    // (js<<5 | jt*4+r); sorted top-4 via min + 3 med3.
    unsigned locb = (unsigned)(js << 5);
    int jb = j0 + quad * 4;
    #pragma unroll
    for (int jt = 0; jt < 8; ++jt) {
      float4 nv = *(const float4*)(nfb + jb + jt * 16);
      float nfa[4] = {nv.x, nv.y, nv.z, nv.w};
      #pragma unroll
      for (int r = 0; r < 4; ++r) {
        float key = fmaf(-2.0f, acc[jt][r], nfa[r]);
        unsigned u = (__float_as_uint(key) & 0xFFFFFF80u) | locb |
                     (unsigned)(jt * 4 + r);
        unsigned m0 = min(ck[0], u);
        unsigned m1 = med3u(ck[0], u, ck[1]);
        unsigned m2 = med3u(ck[1], u, ck[2]);
        unsigned m3 = med3u(ck[2], u, ck[3]);
        ck[0] = m0; ck[1] = m1; ck[2] = m2; ck[3] = m3;
      }
    }

    // one barrier/step: (a) drains DMA into buf[nxt] (vmcnt0 before
    // s_barrier); (b) seals buf[cur] reads before js+2 overwrites it
    __syncthreads();
  }

  // decode stream-local ids -> global j (quad known only pre-merge)
  int cj[4];
  #pragma unroll
  for (int s = 0; s < 4; ++s) {
    unsigned loc = ck[s] & 127u;
    cj[s] = jq0 + (int)((loc >> 5) << 7) + (int)(((loc >> 2) & 7u) << 4) +
            (quad << 2) + (int)(loc & 3u);
  }
  // paired merge across the 4 quads holding the same col (= same i-row)
  #pragma unroll
  for (int m = 16; m < 64; m <<= 1) {
    unsigned tu[4]; int tj[4];
    #pragma unroll
    for (int s = 0; s < 4; ++s) {
      tu[s] = __shfl_xor(ck[s], m, 64);
      tj[s] = __shfl_xor(cj[s], m, 64);
    }
    #pragma unroll
    for (int s = 0; s < 4; ++s) ins4p(tu[s], tj[s], ck, cj);
  }
  if (quad == 0) {
    int row = b * N_DIM + i0 + w * 16 + col;
    unsigned short* cp = cand + row * 16 + q * 4;
    cp[0] = (unsigned short)cj[0];
    cp[1] = (unsigned short)cj[1];
    cp[2] = (unsigned short)cj[2];
    cp[3] = (unsigned short)cj[3];
  }
}

// ---- kernel 3: fused exact-fp64 refine + gather + conv ----
#define NT   64
#define NPAD 68
__global__ __launch_bounds__(256) void conv_kernel(
    const float* __restrict__ xT, const double* __restrict__ nd,
    const unsigned short* __restrict__ cand,
    const float* __restrict__ Wt, const float* __restrict__ bias,
    float* __restrict__ out) {
  __shared__ __align__(16) float nb[C_DIM * K_NN][NPAD];  // 52224 B
  __shared__ unsigned short tks[NT][4];
  int bid = blockIdx.x;
  int b  = bid >> 5;
  int n0 = (bid & 31) * NT;
  const float* xtb = xT + (size_t)b * N_DIM * C_DIM;
  int t = threadIdx.x;
  int w = t >> 6, lane = t & 63;
  int cid = lane >> 2, seg = lane & 3;

  // ---- refine phase: 16 rows per wave ----
  for (int it = 0; it < 16; ++it) {
    int nn = w * 16 + it;
    int row = b * N_DIM + n0 + nn;
    int j = cand[row * 16 + cid];
    const float* xn = xtb + ((size_t)(n0 + nn) * C_DIM) + seg * 16;
    const float* xj = xtb + ((size_t)j * C_DIM) + seg * 16;
    double pd = 0.0;
    #pragma unroll
    for (int qq = 0; qq < 4; ++qq) {
      float4 a  = *(const float4*)(xn + qq * 4);
      float4 bb = *(const float4*)(xj + qq * 4);
      pd = fma((double)a.x, (double)bb.x, pd);
      pd = fma((double)a.y, (double)bb.y, pd);
      pd = fma((double)a.z, (double)bb.z, pd);
      pd = fma((double)a.w, (double)bb.w, pd);
    }
    pd += __shfl_xor(pd, 1, 64);     // reduce over seg
    pd += __shfl_xor(pd, 2, 64);
    double key = fma(-2.0, pd, nd[b * N_DIM + j] + 512.0);  // > 0 always
    unsigned long long u =
        ((unsigned long long)__double_as_longlong(key) & ~2047ull) |
        (unsigned long long)(unsigned)j;
    unsigned long long v = u;
    #pragma unroll
    for (int p = 0; p < 3; ++p) {
      unsigned long long m = v;
      #pragma unroll
      for (int msk = 4; msk < 64; msk <<= 1) {
        unsigned long long o = __shfl_xor(m, msk, 64);
        m = (o < m) ? o : m;
      }
      if (lane == 0) tks[nn][p] = (unsigned short)(m & 2047ull);
      v = (v == m) ? ~0ull : v;      // mask winner (and all equal copies)
    }
  }
  __syncthreads();

  // ---- gather phase ----
  #pragma unroll
  for (int p = 0; p < 12; ++p) {
    int u = p * 256 + t;            // 3072 tasks: 192 rows x 16 segs
    int sg = u & 15;
    int r  = u >> 4;                // r = k*64 + n
    int k = r >> 6, n = r & 63;
    int j = tks[n][k];
    float4 v = *(const float4*)(xtb + (size_t)j * C_DIM + sg * 4);
    nb[(sg * 4 + 0) * 3 + k][n] = v.x;
    nb[(sg * 4 + 1) * 3 + k][n] = v.y;
    nb[(sg * 4 + 2) * 3 + k][n] = v.z;
    nb[(sg * 4 + 3) * 3 + k][n] = v.w;
  }
  __syncthreads();

  // ---- conv phase ----
  int ng = t & 15, og = t >> 4;
  float acc[4][4];
  #pragma unroll
  for (int oo = 0; oo < 4; ++oo) {
    float bv = bias[(og << 2) + oo];
    #pragma unroll
    for (int nn2 = 0; nn2 < 4; ++nn2) acc[oo][nn2] = bv;
  }
  const float* nbp = &nb[0][0] + (ng << 2);
  const float* wtp = Wt + (og << 2);
  #pragma unroll 4
  for (int ckk = 0; ckk < C_DIM * K_NN; ++ckk) {
    float4 nv = *(const float4*)(nbp + ckk * NPAD);
    float4 wv = *(const float4*)(wtp + ckk * O_DIM);
    float na[4] = {nv.x, nv.y, nv.z, nv.w};
    float wa[4] = {wv.x, wv.y, wv.z, wv.w};
    #pragma unroll
    for (int oo = 0; oo < 4; ++oo)
      #pragma unroll
      for (int nn2 = 0; nn2 < 4; ++nn2)
        acc[oo][nn2] = fmaf(wa[oo], na[nn2], acc[oo][nn2]);
  }
  #pragma unroll
  for (int oo = 0; oo < 4; ++oo) {
    int o = (og << 2) + oo;
    float4 v; v.x = acc[oo][0]; v.y = acc[oo][1]; v.z = acc[oo][2]; v.w = acc[oo][3];
    *(float4*)&out[(size_t)(b * O_DIM + o) * N_DIM + n0 + (ng << 2)] = v;
  }
}

extern "C" void kernel_launch(void* const* d_in, const int* in_sizes, int n_in,
                              void* d_out, int out_size, void* d_ws, size_t ws_size,
                              hipStream_t stream) {
  const float* x    = (const float*)d_in[0];   // [B][C][N]
  const float* W    = (const float*)d_in[1];   // [O][C][K]
  const float* bias = (const float*)d_in[2];   // [O]
  float* out = (float*)d_out;                  // [B][O][N]
  char* ws = (char*)d_ws;
  // ws layout (bytes):
  //   xT   fp32 [B][N][C]           @ 0         (8 MB)
  //   xTh  bf16 [B][N][C] swizzled  @ 8388608   (4 MB)
  //   xTl  bf16 [B][N][C] swizzled  @ 12582912  (4 MB)
  //   nd   fp64 [B*N]               @ 16777216  (256 KB)
  //   nf   fp32 [B*N] (norm+512)    @ 17039360  (128 KB)
  //   cand u16  [B*N][16]           @ 17170432  (1 MB)
  //   Wt   fp32 [C*K][O]            @ 18219008  (48 KB)
  float*          xT  = (float*)ws;
  unsigned short* xTh = (unsigned short*)(ws + 8388608);
  unsigned short* xTl = (unsigned short*)(ws + 12582912);
  double*         nd  = (double*)(ws + 16777216);
  float*          nfp = (float*)(ws + 17039360);
  unsigned short* cd  = (unsigned short*)(ws + 17170432);
  float*          Wt  = (float*)(ws + 18219008);

  prep_kernel<<<512 + 48, 256, 0, stream>>>(x, xT, xTh, xTl, nd, nfp, W, Wt);
  topk_kernel<<<B_DIM * 32 * 4, 256, 0, stream>>>(xTh, xTl, nfp, cd);
  conv_kernel<<<B_DIM * (N_DIM / NT), 256, 0, stream>>>(xT, nd, cd, Wt, bias, out);
}